// Round 11
// baseline (121.981 us; speedup 1.0000x reference)
//
#include <hip/hip_runtime.h>

using u16 = unsigned short;
using u64 = unsigned long long;

// Fixed problem shape (guarded in the launcher; generic fallback otherwise).
constexpr int Bc = 2, Tc = 8, Fc = 5, Mc = 128, Sc = 128;
constexpr int Np = 65536;           // points per (b,t) slab
constexpr int QPTS = Np / 4;        // 16384 points per wave-quarter
constexpr int IPTS = 512;           // points per wave per iteration
constexpr int QITERS = QPTS / IPTS; // 32 iterations per quarter

// Largest x with __fsqrt_rn(x) <= r (monotone correctly-rounded sqrt =>
// d2 <= sqrt_ub(r)  <=>  __fsqrt_rn(d2) <= r : the reference predicate, bit-exact).
__device__ __forceinline__ float sqrt_ub(float r) {
    float u = __fmul_rn(r, r);
    if (__fsqrt_rn(u) <= r) {
        while (true) {
            float nu = __uint_as_float(__float_as_uint(u) + 1u);
            if (__fsqrt_rn(nu) <= r) u = nu; else break;
        }
    } else {
        while (__fsqrt_rn(u) > r) u = __uint_as_float(__float_as_uint(u) - 1u);
    }
    return u;
}

__device__ __forceinline__ float box_radius(const float* __restrict__ box) {
    const float hl = __fmul_rn(0.5f, box[3]);
    const float hw = __fmul_rn(0.5f, box[4]);
    return __fmul_rn(__fsqrt_rn(__fadd_rn(__fmul_rn(hl, hl), __fmul_rn(hw, hw))), 1.1f);
}

// One block per (b,t,m) box; 4 waves, each owning a contiguous quarter of the
// slab. Phase A: barrier-free streaming count (per-iter hit counts -> private
// LDS row; early exit at personal cap 128). ONE __syncthreads. Phase B/C:
// 4-entry prefix -> base; emit walks recorded counts, skips zero-hit iters,
// recomputes the predicate only where it emits. Tail zeroed last.
__global__ __launch_bounds__(256) void k_box(
    const float* __restrict__ points,        // [B,T,N,F]
    const float* __restrict__ rois,          // [B,T,M,7]
    const int*   __restrict__ vlen,          // [B,T,M]
    float*       __restrict__ out)           // [B,M,T,S,F]
{
    const int blk = blockIdx.x;
    const int m  = blk & (Mc - 1);           // 128 consecutive blocks share a slab
    const int bt = blk >> 7;
    const int t = bt & 7, b = bt >> 3;

    // fallback rows (t!=0, vlen==0) recompute the frame-0 pooling exactly
    int t_eff = t;
    if (t != 0 && vlen[bt * Mc + m] == 0) t_eff = 0;
    const int btE = b * Tc + t_eff;

    const float* box = rois + (size_t)(btE * Mc + m) * 7;
    const float cx = box[0], cy = box[1];
    const float T = sqrt_ub(box_radius(box));
    const float* pts = points + (size_t)btE * Np * Fc;
    float* orow = out + (size_t)((b * Mc + m) * Tc + t) * (Sc * Fc);

    __shared__ int s_wcnt[4];
    __shared__ int s_iters[4];
    __shared__ u16 s_cnt[4][QITERS];

    const int tid = threadIdx.x, lane = tid & 63, wv = tid >> 6;
    const u64 lt = (1ull << lane) - 1ull;

    // ---------------- Phase A: barrier-free streaming count ----------------
    int c = 0;
    int it = 0;
    while (it < QITERS) {
        const int pbase = wv * QPTS + it * IPTS;
        int cc = 0;
        #pragma unroll
        for (int h = 0; h < 2; ++h) {
            // lane owns 4 consecutive points: 4 pts x 5 floats = 5 float4s
            const float4* src = (const float4*)(pts + (size_t)(pbase + h * 256 + lane * 4) * Fc);
            const float4 v0 = src[0], v1 = src[1], v2 = src[2], v3 = src[3], v4 = src[4];
            const float qx0 = v0.x, qy0 = v0.y;
            const float qx1 = v1.y, qy1 = v1.z;
            const float qx2 = v2.z, qy2 = v2.w;
            const float qx3 = v3.w, qy3 = v4.x;
            #pragma unroll
            for (int k = 0; k < 4; ++k) {
                const float qx = k == 0 ? qx0 : k == 1 ? qx1 : k == 2 ? qx2 : qx3;
                const float qy = k == 0 ? qy0 : k == 1 ? qy1 : k == 2 ? qy2 : qy3;
                const float dx = __fsub_rn(qx, cx);
                const float dy = __fsub_rn(qy, cy);
                const float d2 = __fadd_rn(__fmul_rn(dx, dx), __fmul_rn(dy, dy));
                cc += (int)__popcll(__ballot(d2 <= T));
            }
        }
        if (lane == 0) s_cnt[wv][it] = (u16)cc;
        c += cc;
        ++it;
        if (c >= Sc) break;                   // wave-uniform personal cap
    }
    if (lane == 0) { s_wcnt[wv] = c < Sc ? c : Sc; s_iters[wv] = it; }

    __syncthreads();                          // the only barrier in the kernel

    // ---------------- Phase B: prefix over 4 wave counts --------------------
    const int c0 = s_wcnt[0], c1 = s_wcnt[1], c2 = s_wcnt[2], c3 = s_wcnt[3];
    const int total = c0 + c1 + c2 + c3;
    int base = 0;
    if (wv > 0) base += c0;
    if (wv > 1) base += c1;
    if (wv > 2) base += c2;
    const int myiters = s_iters[wv];

    // ---------------- Phase C: emit (work proportional to hits) -------------
    if (base < Sc) {
        int slot = base;
        for (int i2 = 0; i2 < myiters && slot < Sc; ++i2) {
            const int cc = (int)s_cnt[wv][i2];
            if (cc == 0) continue;
            const int pbase = wv * QPTS + i2 * IPTS;
            int sb = slot;
            #pragma unroll
            for (int h = 0; h < 2; ++h) {
                const float4* src = (const float4*)(pts + (size_t)(pbase + h * 256 + lane * 4) * Fc);
                const float4 v0 = src[0], v1 = src[1], v2 = src[2], v3 = src[3], v4 = src[4];
                float f[20];
                *(float4*)&f[0]  = v0; *(float4*)&f[4]  = v1; *(float4*)&f[8]  = v2;
                *(float4*)&f[12] = v3; *(float4*)&f[16] = v4;
                u64 bal[4];
                int below = 0, toth = 0;
                #pragma unroll
                for (int k = 0; k < 4; ++k) {
                    const float dx = __fsub_rn(f[5 * k + 0], cx);
                    const float dy = __fsub_rn(f[5 * k + 1], cy);
                    const float d2 = __fadd_rn(__fmul_rn(dx, dx), __fmul_rn(dy, dy));
                    bal[k] = __ballot(d2 <= T);
                    below += (int)__popcll(bal[k] & lt);
                    toth  += (int)__popcll(bal[k]);
                }
                int ownpre = 0;
                #pragma unroll
                for (int k = 0; k < 4; ++k) {
                    if ((bal[k] >> lane) & 1ull) {
                        const int sk = sb + below + ownpre;
                        if (sk < Sc) {
                            float* o = orow + (size_t)sk * Fc;
                            o[0] = f[5*k+0]; o[1] = f[5*k+1]; o[2] = f[5*k+2];
                            o[3] = f[5*k+3]; o[4] = f[5*k+4];
                        }
                        ++ownpre;
                    }
                }
                sb += toth;
            }
            slot = sb;
        }
    }

    // ---------------- tail zero [min(total,S), S) ----------------------------
    const int fill = total < Sc ? total : Sc;
    for (int i = fill * Fc + tid; i < Sc * Fc; i += 256) orow[i] = 0.0f;
}

// ---------------- fallback: R2 single-kernel path (shape-generic) ------------
__global__ __launch_bounds__(1024) void vox_pool(
    const float* __restrict__ points, const float* __restrict__ rois,
    const int* __restrict__ valid_length, float* __restrict__ out,
    int N, int M, int S)
{
    const int blk = blockIdx.x;
    const int m = blk % M;
    const int t = (blk / M) % Tc;
    const int b = blk / (M * Tc);
    int t_eff = t;
    if (t != 0 && valid_length[(b * Tc + t) * M + m] == 0) t_eff = 0;
    const float* box = rois + (size_t)((b * Tc + t_eff) * M + m) * 7;
    const float cx = box[0], cy = box[1];
    const float r = box_radius(box);
    const float* pts = points + (size_t)(b * Tc + t_eff) * N * Fc;
    float* o = out + ((size_t)(b * M + m) * Tc + t) * (size_t)S * Fc;
    __shared__ int wcnt[16];
    const int tid = threadIdx.x, lane = tid & 63, wav = tid >> 6;
    const int nthreads = blockDim.x, nwaves = nthreads >> 6;
    int cnt = 0;
    for (int basei = 0; basei < N; basei += nthreads) {
        const int idx = basei + tid;
        bool inside = false;
        if (idx < N) {
            const float dx = __fsub_rn(pts[(size_t)idx * Fc + 0], cx);
            const float dy = __fsub_rn(pts[(size_t)idx * Fc + 1], cy);
            const float d2 = __fadd_rn(__fmul_rn(dx, dx), __fmul_rn(dy, dy));
            inside = (__fsqrt_rn(d2) <= r);
        }
        const unsigned long long bal = __ballot(inside);
        if (lane == 0) wcnt[wav] = __popcll(bal);
        __syncthreads();
        int wave_off = 0, block_tot = 0;
        for (int w = 0; w < nwaves; ++w) {
            const int c = wcnt[w];
            if (w < wav) wave_off += c;
            block_tot += c;
        }
        if (inside) {
            const int slot = cnt + wave_off + (int)__popcll(bal & ((1ull << lane) - 1ull));
            if (slot < S)
                for (int f = 0; f < Fc; ++f)
                    o[(size_t)slot * Fc + f] = pts[(size_t)idx * Fc + f];
        }
        cnt += block_tot;
        __syncthreads();
        if (cnt >= S) break;
    }
    const int filled = cnt < S ? cnt : S;
    for (int s = filled + tid; s < S; s += nthreads)
        for (int f = 0; f < Fc; ++f)
            o[(size_t)s * Fc + f] = 0.0f;
}

extern "C" void kernel_launch(void* const* d_in, const int* in_sizes, int n_in,
                              void* d_out, int out_size, void* d_ws, size_t ws_size,
                              hipStream_t stream) {
    const float* points = (const float*)d_in[0];
    const float* rois   = (const float*)d_in[1];
    const int*   vlen   = (const int*)d_in[2];
    float* out = (float*)d_out;

    const bool fixed =
        in_sizes[0] == Bc * Tc * Np * Fc &&
        in_sizes[1] == Bc * Tc * Mc * 7 &&
        in_sizes[2] == Bc * Tc * Mc &&
        out_size    == Bc * Mc * Tc * Sc * Fc;

    if (fixed) {
        k_box<<<dim3(Bc * Tc * Mc), 256, 0, stream>>>(points, rois, vlen, out);
    } else {
        const int N = in_sizes[0] / (Bc * Tc * Fc);
        const int M = in_sizes[2] / (Bc * Tc);
        const int S = out_size / (Bc * M * Tc * Fc);
        vox_pool<<<dim3(Bc * Tc * M), 1024, 0, stream>>>(points, rois, vlen, out, N, M, S);
    }
}

// Round 12
// 88.970 us; speedup vs baseline: 1.3710x; 1.3710x over previous
//
#include <hip/hip_runtime.h>

using u16 = unsigned short;
using u32 = unsigned int;
using u64 = unsigned long long;

// Fixed problem shape (guarded in the launcher; generic fallback otherwise).
constexpr int Bc = 2, Tc = 8, Fc = 5, Mc = 128, Sc = 128;
constexpr int Np = 65536;           // points per (b,t) slab
constexpr int CPTS = 512;           // points per chunk (8 per lane)
constexpr int NCHK = Np / CPTS;     // 128 chunks per slab
constexpr int NB = 31;              // phase-B chunks per wave (chunks 4..127)

// Largest x with __fsqrt_rn(x) <= r (monotone correctly-rounded sqrt =>
// d2 <= sqrt_ub(r)  <=>  __fsqrt_rn(d2) <= r : the reference predicate, bit-exact).
__device__ __forceinline__ float sqrt_ub(float r) {
    float u = __fmul_rn(r, r);
    if (__fsqrt_rn(u) <= r) {
        while (true) {
            float nu = __uint_as_float(__float_as_uint(u) + 1u);
            if (__fsqrt_rn(nu) <= r) u = nu; else break;
        }
    } else {
        while (__fsqrt_rn(u) > r) u = __uint_as_float(__float_as_uint(u) - 1u);
    }
    return u;
}

__device__ __forceinline__ float box_radius(const float* __restrict__ box) {
    const float hl = __fmul_rn(0.5f, box[3]);
    const float hw = __fmul_rn(0.5f, box[4]);
    return __fmul_rn(__fsqrt_rn(__fadd_rn(__fmul_rn(hl, hl), __fmul_rn(hw, hw))), 1.1f);
}

// One block per (b,t,m) box; 4 waves. Phase A: one 2048-pt round, masks in
// regs, one barrier; >=128 hits -> emit & exit (common case). Survivors:
// Phase B fixed-trip barrier-free streaming count of 31 chunks/wave (counts ->
// LDS), one barrier, wave-wide shfl prefix over all 128 chunk counts ->
// exact per-chunk output bases, then a fixed-trip independent-chunk emit.
// No running counters across iterations => every long loop is pipelineable.
__global__ __launch_bounds__(256) void k_box(
    const float* __restrict__ points,        // [B,T,N,F]
    const float* __restrict__ rois,          // [B,T,M,7]
    const int*   __restrict__ vlen,          // [B,T,M]
    float*       __restrict__ out)           // [B,M,T,S,F]
{
    const int blk = blockIdx.x;
    const int bt = blk & 15;                 // blk%8 == bt%8: slab -> XCD pinning
    const int m  = blk >> 4;
    const int t = bt & 7, b = bt >> 3;

    // fallback rows (t!=0, vlen==0) recompute the frame-0 pooling exactly
    int t_eff = t;
    if (t != 0 && vlen[bt * Mc + m] == 0) t_eff = 0;
    const int btE = b * Tc + t_eff;

    const float* box = rois + (size_t)(btE * Mc + m) * 7;
    const float cx = box[0], cy = box[1];
    const float T = sqrt_ub(box_radius(box));
    const float* pts = points + (size_t)btE * Np * Fc;
    float* orow = out + (size_t)((b * Mc + m) * Tc + t) * (Sc * Fc);

    __shared__ u16 s_cnt[NCHK];              // per-chunk hit counts (128)

    const int tid = threadIdx.x, lane = tid & 63, wv = tid >> 6;
    const u64 lt = (1ull << lane) - 1ull;

    // ---------------- Phase A: count chunk wv (masks kept in regs) ----------
    float pxA[8], pyA[8];
    {
        const int pbase = wv * CPTS;
        #pragma unroll
        for (int i = 0; i < 8; ++i) {
            const size_t idx = (size_t)(pbase + i * 64 + lane);
            pxA[i] = pts[idx * Fc + 0];
            pyA[i] = pts[idx * Fc + 1];
        }
    }
    u64 balA[8]; int cA = 0;
    #pragma unroll
    for (int i = 0; i < 8; ++i) {
        const float dx = __fsub_rn(pxA[i], cx);
        const float dy = __fsub_rn(pyA[i], cy);
        const float d2 = __fadd_rn(__fmul_rn(dx, dx), __fmul_rn(dy, dy));
        balA[i] = __ballot(d2 <= T);
        cA += (int)__popcll(balA[i]);
    }
    if (lane == 0) s_cnt[wv] = (u16)cA;
    __syncthreads();

    const int c0 = s_cnt[0], c1 = s_cnt[1], c2 = s_cnt[2], c3 = s_cnt[3];
    const int cum4 = c0 + c1 + c2 + c3;
    int baseA = 0;
    if (wv > 0) baseA += c0;
    if (wv > 1) baseA += c1;
    if (wv > 2) baseA += c2;

    if (cum4 >= Sc) {
        // -------- fast path: first 2048 points already fill all S slots -----
        if (baseA < Sc && cA > 0) {
            int sb = baseA;
            const int pbase = wv * CPTS;
            #pragma unroll
            for (int i = 0; i < 8; ++i) {
                if ((balA[i] >> lane) & 1ull) {
                    const int slot = sb + (int)__popcll(balA[i] & lt);
                    if (slot < Sc) {
                        const size_t idx = (size_t)(pbase + i * 64 + lane);
                        float* o = orow + (size_t)slot * Fc;
                        o[0] = pxA[i]; o[1] = pyA[i];
                        o[2] = pts[idx * Fc + 2];
                        o[3] = pts[idx * Fc + 3];
                        o[4] = pts[idx * Fc + 4];
                    }
                }
                sb += (int)__popcll(balA[i]);
            }
        }
        return;                               // no tail: slots [0,S) all written
    }

    // ---------------- Phase B: fixed-trip streaming count (no barrier) ------
    // wave wv owns chunks c = 4 + 4j + wv, j = 0..30. 1-deep register prefetch;
    // no early exit and no fences => iterations overlap.
    {
        float px[8], py[8];
        {
            const int pbase = (4 + wv) * CPTS;
            #pragma unroll
            for (int i = 0; i < 8; ++i) {
                const size_t idx = (size_t)(pbase + i * 64 + lane);
                px[i] = pts[idx * Fc + 0];
                py[i] = pts[idx * Fc + 1];
            }
        }
        for (int j = 0; j < NB; ++j) {
            float nx[8], ny[8];
            if (j + 1 < NB) {
                const int pbase = (4 + 4 * (j + 1) + wv) * CPTS;
                #pragma unroll
                for (int i = 0; i < 8; ++i) {
                    const size_t idx = (size_t)(pbase + i * 64 + lane);
                    nx[i] = pts[idx * Fc + 0];
                    ny[i] = pts[idx * Fc + 1];
                }
            }
            int cc = 0;
            #pragma unroll
            for (int i = 0; i < 8; ++i) {
                const float dx = __fsub_rn(px[i], cx);
                const float dy = __fsub_rn(py[i], cy);
                const float d2 = __fadd_rn(__fmul_rn(dx, dx), __fmul_rn(dy, dy));
                cc += (int)__popcll(__ballot(d2 <= T));
            }
            if (lane == 0) s_cnt[4 + 4 * j + wv] = (u16)cc;
            if (j + 1 < NB) {
                #pragma unroll
                for (int i = 0; i < 8; ++i) { px[i] = nx[i]; py[i] = ny[i]; }
            }
        }
    }
    __syncthreads();

    // ---------------- prefix over 128 chunk counts (shfl scan, per wave) ----
    const u32 two = ((const u32*)s_cnt)[lane];   // counts of chunks 2*lane, 2*lane+1
    const int av  = (int)(two & 0xFFFFu);
    const int av2 = (int)(two >> 16);
    const int ssum = av + av2;
    int incl = ssum;
    #pragma unroll
    for (int d = 1; d < 64; d <<= 1) { int v = __shfl_up(incl, d); if (lane >= d) incl += v; }
    const int excl  = incl - ssum;               // base of chunk 2*lane
    const int total = __shfl(incl, 63);

    // jcap: how many of MY phase-B chunks have base < Sc (bases monotone).
    // my chunk j sits at lane 2+2j+(wv>>1), element parity wv&1.
    const int okv = (wv & 1) ? (excl + av) : excl;
    const u64 okb = __ballot(okv < Sc);
    const u64 wvmask = (wv < 2) ? 0x5555555555555554ull : 0xAAAAAAAAAAAAAAA8ull;
    const int jcap = (int)__popcll(okb & wvmask);

    // ---------------- emit phase A from regs (all slots < cum4 < Sc) --------
    if (cA > 0) {
        int sb = baseA;
        const int pbase = wv * CPTS;
        #pragma unroll
        for (int i = 0; i < 8; ++i) {
            if ((balA[i] >> lane) & 1ull) {
                const int slot = sb + (int)__popcll(balA[i] & lt);
                const size_t idx = (size_t)(pbase + i * 64 + lane);
                float* o = orow + (size_t)slot * Fc;
                o[0] = pxA[i]; o[1] = pyA[i];
                o[2] = pts[idx * Fc + 2];
                o[3] = pts[idx * Fc + 3];
                o[4] = pts[idx * Fc + 4];
            }
            sb += (int)__popcll(balA[i]);
        }
    }

    // ---------------- Phase D: emit my chunks j < jcap (fixed trip) ---------
    if (jcap > 0) {
        float px[8], py[8];
        {
            const int pbase = (4 + wv) * CPTS;
            #pragma unroll
            for (int i = 0; i < 8; ++i) {
                const size_t idx = (size_t)(pbase + i * 64 + lane);
                px[i] = pts[idx * Fc + 0];
                py[i] = pts[idx * Fc + 1];
            }
        }
        for (int j = 0; j < jcap; ++j) {
            float nx[8], ny[8];
            if (j + 1 < jcap) {
                const int pbase = (4 + 4 * (j + 1) + wv) * CPTS;
                #pragma unroll
                for (int i = 0; i < 8; ++i) {
                    const size_t idx = (size_t)(pbase + i * 64 + lane);
                    nx[i] = pts[idx * Fc + 0];
                    ny[i] = pts[idx * Fc + 1];
                }
            }
            const int c = 4 + 4 * j + wv;
            const int sl = c >> 1;
            int bc = __shfl(excl, sl);
            if (c & 1) bc += __shfl(av, sl);     // exact base of chunk c

            const int pbase = c * CPTS;
            int sb = bc;
            #pragma unroll
            for (int i = 0; i < 8; ++i) {
                const float dx = __fsub_rn(px[i], cx);
                const float dy = __fsub_rn(py[i], cy);
                const float d2 = __fadd_rn(__fmul_rn(dx, dx), __fmul_rn(dy, dy));
                const bool inside = (d2 <= T);
                const u64 bal = __ballot(inside);
                if (inside) {
                    const int slot = sb + (int)__popcll(bal & lt);
                    if (slot < Sc) {
                        const size_t idx = (size_t)(pbase + i * 64 + lane);
                        float* o = orow + (size_t)slot * Fc;
                        o[0] = px[i]; o[1] = py[i];
                        o[2] = pts[idx * Fc + 2];
                        o[3] = pts[idx * Fc + 3];
                        o[4] = pts[idx * Fc + 4];
                    }
                }
                sb += (int)__popcll(bal);
            }
            if (j + 1 < jcap) {
                #pragma unroll
                for (int i = 0; i < 8; ++i) { px[i] = nx[i]; py[i] = ny[i]; }
            }
        }
    }

    // ---------------- tail zero [min(total,S), S) ---------------------------
    const int fill = total < Sc ? total : Sc;
    for (int i = fill * Fc + tid; i < Sc * Fc; i += 256) orow[i] = 0.0f;
}

// ---------------- fallback: R2 single-kernel path (shape-generic) ------------
__global__ __launch_bounds__(1024) void vox_pool(
    const float* __restrict__ points, const float* __restrict__ rois,
    const int* __restrict__ valid_length, float* __restrict__ out,
    int N, int M, int S)
{
    const int blk = blockIdx.x;
    const int m = blk % M;
    const int t = (blk / M) % Tc;
    const int b = blk / (M * Tc);
    int t_eff = t;
    if (t != 0 && valid_length[(b * Tc + t) * M + m] == 0) t_eff = 0;
    const float* box = rois + (size_t)((b * Tc + t_eff) * M + m) * 7;
    const float cx = box[0], cy = box[1];
    const float r = box_radius(box);
    const float* pts = points + (size_t)(b * Tc + t_eff) * N * Fc;
    float* o = out + ((size_t)(b * M + m) * Tc + t) * (size_t)S * Fc;
    __shared__ int wcnt[16];
    const int tid = threadIdx.x, lane = tid & 63, wav = tid >> 6;
    const int nthreads = blockDim.x, nwaves = nthreads >> 6;
    int cnt = 0;
    for (int basei = 0; basei < N; basei += nthreads) {
        const int idx = basei + tid;
        bool inside = false;
        if (idx < N) {
            const float dx = __fsub_rn(pts[(size_t)idx * Fc + 0], cx);
            const float dy = __fsub_rn(pts[(size_t)idx * Fc + 1], cy);
            const float d2 = __fadd_rn(__fmul_rn(dx, dx), __fmul_rn(dy, dy));
            inside = (__fsqrt_rn(d2) <= r);
        }
        const unsigned long long bal = __ballot(inside);
        if (lane == 0) wcnt[wav] = __popcll(bal);
        __syncthreads();
        int wave_off = 0, block_tot = 0;
        for (int w = 0; w < nwaves; ++w) {
            const int c = wcnt[w];
            if (w < wav) wave_off += c;
            block_tot += c;
        }
        if (inside) {
            const int slot = cnt + wave_off + (int)__popcll(bal & ((1ull << lane) - 1ull));
            if (slot < S)
                for (int f = 0; f < Fc; ++f)
                    o[(size_t)slot * Fc + f] = pts[(size_t)idx * Fc + f];
        }
        cnt += block_tot;
        __syncthreads();
        if (cnt >= S) break;
    }
    const int filled = cnt < S ? cnt : S;
    for (int s = filled + tid; s < S; s += nthreads)
        for (int f = 0; f < Fc; ++f)
            o[(size_t)s * Fc + f] = 0.0f;
}

extern "C" void kernel_launch(void* const* d_in, const int* in_sizes, int n_in,
                              void* d_out, int out_size, void* d_ws, size_t ws_size,
                              hipStream_t stream) {
    const float* points = (const float*)d_in[0];
    const float* rois   = (const float*)d_in[1];
    const int*   vlen   = (const int*)d_in[2];
    float* out = (float*)d_out;

    const bool fixed =
        in_sizes[0] == Bc * Tc * Np * Fc &&
        in_sizes[1] == Bc * Tc * Mc * 7 &&
        in_sizes[2] == Bc * Tc * Mc &&
        out_size    == Bc * Mc * Tc * Sc * Fc;

    if (fixed) {
        k_box<<<dim3(Bc * Tc * Mc), 256, 0, stream>>>(points, rois, vlen, out);
    } else {
        const int N = in_sizes[0] / (Bc * Tc * Fc);
        const int M = in_sizes[2] / (Bc * Tc);
        const int S = out_size / (Bc * M * Tc * Fc);
        vox_pool<<<dim3(Bc * Tc * M), 1024, 0, stream>>>(points, rois, vlen, out, N, M, S);
    }
}

// Round 13
// 81.169 us; speedup vs baseline: 1.5028x; 1.0961x over previous
//
#include <hip/hip_runtime.h>

using u16 = unsigned short;
using u32 = unsigned int;
using u64 = unsigned long long;

// Fixed problem shape (guarded in the launcher; generic fallback otherwise).
constexpr int Bc = 2, Tc = 8, Fc = 5, Mc = 128, Sc = 128;
constexpr int Np = 65536;           // points per (b,t) slab
constexpr int CPTS = 512;           // points per chunk (8 per lane)
constexpr int NCHK = Np / CPTS;     // 128 chunks per slab

// Largest x with __fsqrt_rn(x) <= r (monotone correctly-rounded sqrt =>
// d2 <= sqrt_ub(r)  <=>  __fsqrt_rn(d2) <= r : the reference predicate, bit-exact).
__device__ __forceinline__ float sqrt_ub(float r) {
    float u = __fmul_rn(r, r);
    if (__fsqrt_rn(u) <= r) {
        while (true) {
            float nu = __uint_as_float(__float_as_uint(u) + 1u);
            if (__fsqrt_rn(nu) <= r) u = nu; else break;
        }
    } else {
        while (__fsqrt_rn(u) > r) u = __uint_as_float(__float_as_uint(u) - 1u);
    }
    return u;
}

__device__ __forceinline__ float box_radius(const float* __restrict__ box) {
    const float hl = __fmul_rn(0.5f, box[3]);
    const float hw = __fmul_rn(0.5f, box[4]);
    return __fmul_rn(__fsqrt_rn(__fadd_rn(__fmul_rn(hl, hl), __fmul_rn(hw, hw))), 1.1f);
}

// One block per (b,t,m) box; 4 waves. Stage 1: count chunks 0..7 (masks ->
// LDS), one barrier; if >=S hits, emit winners from masks and exit. Stage 2
// (survivors): fixed-trip count of chunks 8..127 (masks -> LDS), one barrier,
// shfl-prefix over all 128 counts, winners-only emit from stored masks
// (scattered payload loads, <=S points), tail zero. No re-scan, no rotation.
__global__ __launch_bounds__(256) void k_box(
    const float* __restrict__ points,        // [B,T,N,F]
    const float* __restrict__ rois,          // [B,T,M,7]
    const int*   __restrict__ vlen,          // [B,T,M]
    float*       __restrict__ out)           // [B,M,T,S,F]
{
    const int blk = blockIdx.x;
    const int bt = blk & 15;                 // slab -> XCD pinning (blk%8 == bt%8)
    const int m  = blk >> 4;
    const int t = bt & 7, b = bt >> 3;

    int t_eff = t;
    if (t != 0 && vlen[bt * Mc + m] == 0) t_eff = 0;   // frame-0 fallback
    const int btE = b * Tc + t_eff;

    const float* box = rois + (size_t)(btE * Mc + m) * 7;
    const float cx = box[0], cy = box[1];
    const float T = sqrt_ub(box_radius(box));
    const float* pts = points + (size_t)btE * Np * Fc;
    float* orow = out + (size_t)((b * Mc + m) * Tc + t) * (Sc * Fc);

    __shared__ u64 s_bal[NCHK][8];           // 8 KB: ballot masks, group (h,k)
    __shared__ u16 s_cnt[NCHK];              // per-chunk hit counts

    const int tid = threadIdx.x, lane = tid & 63, wv = tid >> 6;
    const u64 lt = (1ull << lane) - 1ull;

    // ---- count one 512-pt chunk: masks -> s_bal[c][h*4+k], count -> s_cnt[c]
    // point (h,k,l) has in-chunk index h*256 + 4*l + k (float4 load pattern).
    auto count_chunk = [&](int c) {
        const float* pc = pts + (size_t)c * CPTS * Fc;
        int cc = 0;
        #pragma unroll
        for (int h = 0; h < 2; ++h) {
            const float4* src = (const float4*)(pc + (size_t)(h * 256 + lane * 4) * Fc);
            const float4 v0 = src[0], v1 = src[1], v2 = src[2], v3 = src[3], v4 = src[4];
            const float qx0 = v0.x, qy0 = v0.y;
            const float qx1 = v1.y, qy1 = v1.z;
            const float qx2 = v2.z, qy2 = v2.w;
            const float qx3 = v3.w, qy3 = v4.x;
            #pragma unroll
            for (int k = 0; k < 4; ++k) {
                const float qx = k == 0 ? qx0 : k == 1 ? qx1 : k == 2 ? qx2 : qx3;
                const float qy = k == 0 ? qy0 : k == 1 ? qy1 : k == 2 ? qy2 : qy3;
                const float dx = __fsub_rn(qx, cx);
                const float dy = __fsub_rn(qy, cy);
                const float d2 = __fadd_rn(__fmul_rn(dx, dx), __fmul_rn(dy, dy));
                const u64 bb = __ballot(d2 <= T);
                if (lane == 0) s_bal[c][h * 4 + k] = bb;
                cc += (int)__popcll(bb);
            }
        }
        if (lane == 0) s_cnt[c] = (u16)cc;
    };

    // ---- emit chunk c's winners from stored masks; returns base + count ----
    // slot of point (h,k,l) = sb + (winners in lanes < l, all k) + (winners in
    // my lane with k' < k)  — exact ascending-index compaction (R11-verified).
    auto emit_chunk = [&](int c, int sb) -> int {
        #pragma unroll
        for (int h = 0; h < 2; ++h) {
            const u64 b0 = s_bal[c][h * 4 + 0];
            const u64 b1 = s_bal[c][h * 4 + 1];
            const u64 b2 = s_bal[c][h * 4 + 2];
            const u64 b3 = s_bal[c][h * 4 + 3];
            const int below = (int)(__popcll(b0 & lt) + __popcll(b1 & lt) +
                                    __popcll(b2 & lt) + __popcll(b3 & lt));
            const int pidx0 = c * CPTS + h * 256 + lane * 4;
            int ownpre = 0;
            #pragma unroll
            for (int k = 0; k < 4; ++k) {
                const u64 bk = k == 0 ? b0 : k == 1 ? b1 : k == 2 ? b2 : b3;
                if ((bk >> lane) & 1ull) {
                    const int slot = sb + below + ownpre;
                    if (slot < Sc) {
                        const float* p = pts + (size_t)(pidx0 + k) * Fc;
                        float* o = orow + (size_t)slot * Fc;
                        o[0] = p[0]; o[1] = p[1]; o[2] = p[2]; o[3] = p[3]; o[4] = p[4];
                    }
                    ++ownpre;
                }
            }
            sb += (int)(__popcll(b0) + __popcll(b1) + __popcll(b2) + __popcll(b3));
        }
        return sb;
    };

    // ================= Stage 1: chunks 0..7 (4096 points) ===================
    count_chunk(wv);
    count_chunk(4 + wv);
    __syncthreads();

    int pre[9];
    pre[0] = 0;
    #pragma unroll
    for (int k = 0; k < 8; ++k) pre[k + 1] = pre[k] + (int)s_cnt[k];
    const int total8 = pre[8];

    if (total8 >= Sc) {
        if (pre[wv] < Sc)     emit_chunk(wv,     pre[wv]);
        if (pre[4 + wv] < Sc) emit_chunk(4 + wv, pre[4 + wv]);
        return;                               // all S slots written
    }

    // ================= Stage 2: chunks 8..127 (fixed trip, flat) ============
    #pragma unroll 2
    for (int j = 0; j < 30; ++j)
        count_chunk(8 + 4 * j + wv);
    __syncthreads();

    // shfl-prefix over all 128 chunk counts (2 u16 per lane)
    const u32 two = ((const u32*)s_cnt)[lane];
    const int av  = (int)(two & 0xFFFFu);
    const int av2 = (int)(two >> 16);
    const int ssum = av + av2;
    int incl = ssum;
    #pragma unroll
    for (int d = 1; d < 64; d <<= 1) { int v = __shfl_up(incl, d); if (lane >= d) incl += v; }
    const int excl  = incl - ssum;            // base of chunk 2*lane
    const int total = __shfl(incl, 63);

    // winners-only emit over owned chunks c = 4j+wv (incl. 0..7 from stage 1)
    for (int j = 0; j < 32; ++j) {
        const int c = 4 * j + wv;
        const int cc = (int)s_cnt[c];
        if (cc == 0) continue;
        const int sl = c >> 1;
        int base = __shfl(excl, sl);
        if (c & 1) base += __shfl(av, sl);
        if (base >= Sc) break;                // bases monotone in j for my wave
        emit_chunk(c, base);
    }

    // tail zero [min(total,S), S)
    const int fill = total < Sc ? total : Sc;
    for (int i = fill * Fc + tid; i < Sc * Fc; i += 256) orow[i] = 0.0f;
}

// ---------------- fallback: R2 single-kernel path (shape-generic) ------------
__global__ __launch_bounds__(1024) void vox_pool(
    const float* __restrict__ points, const float* __restrict__ rois,
    const int* __restrict__ valid_length, float* __restrict__ out,
    int N, int M, int S)
{
    const int blk = blockIdx.x;
    const int m = blk % M;
    const int t = (blk / M) % Tc;
    const int b = blk / (M * Tc);
    int t_eff = t;
    if (t != 0 && valid_length[(b * Tc + t) * M + m] == 0) t_eff = 0;
    const float* box = rois + (size_t)((b * Tc + t_eff) * M + m) * 7;
    const float cx = box[0], cy = box[1];
    const float r = box_radius(box);
    const float* pts = points + (size_t)(b * Tc + t_eff) * N * Fc;
    float* o = out + ((size_t)(b * M + m) * Tc + t) * (size_t)S * Fc;
    __shared__ int wcnt[16];
    const int tid = threadIdx.x, lane = tid & 63, wav = tid >> 6;
    const int nthreads = blockDim.x, nwaves = nthreads >> 6;
    int cnt = 0;
    for (int basei = 0; basei < N; basei += nthreads) {
        const int idx = basei + tid;
        bool inside = false;
        if (idx < N) {
            const float dx = __fsub_rn(pts[(size_t)idx * Fc + 0], cx);
            const float dy = __fsub_rn(pts[(size_t)idx * Fc + 1], cy);
            const float d2 = __fadd_rn(__fmul_rn(dx, dx), __fmul_rn(dy, dy));
            inside = (__fsqrt_rn(d2) <= r);
        }
        const unsigned long long bal = __ballot(inside);
        if (lane == 0) wcnt[wav] = __popcll(bal);
        __syncthreads();
        int wave_off = 0, block_tot = 0;
        for (int w = 0; w < nwaves; ++w) {
            const int c = wcnt[w];
            if (w < wav) wave_off += c;
            block_tot += c;
        }
        if (inside) {
            const int slot = cnt + wave_off + (int)__popcll(bal & ((1ull << lane) - 1ull));
            if (slot < S)
                for (int f = 0; f < Fc; ++f)
                    o[(size_t)slot * Fc + f] = pts[(size_t)idx * Fc + f];
        }
        cnt += block_tot;
        __syncthreads();
        if (cnt >= S) break;
    }
    const int filled = cnt < S ? cnt : S;
    for (int s = filled + tid; s < S; s += nthreads)
        for (int f = 0; f < Fc; ++f)
            o[(size_t)s * Fc + f] = 0.0f;
}

extern "C" void kernel_launch(void* const* d_in, const int* in_sizes, int n_in,
                              void* d_out, int out_size, void* d_ws, size_t ws_size,
                              hipStream_t stream) {
    const float* points = (const float*)d_in[0];
    const float* rois   = (const float*)d_in[1];
    const int*   vlen   = (const int*)d_in[2];
    float* out = (float*)d_out;

    const bool fixed =
        in_sizes[0] == Bc * Tc * Np * Fc &&
        in_sizes[1] == Bc * Tc * Mc * 7 &&
        in_sizes[2] == Bc * Tc * Mc &&
        out_size    == Bc * Mc * Tc * Sc * Fc;

    if (fixed) {
        k_box<<<dim3(Bc * Tc * Mc), 256, 0, stream>>>(points, rois, vlen, out);
    } else {
        const int N = in_sizes[0] / (Bc * Tc * Fc);
        const int M = in_sizes[2] / (Bc * Tc);
        const int S = out_size / (Bc * M * Tc * Fc);
        vox_pool<<<dim3(Bc * Tc * M), 1024, 0, stream>>>(points, rois, vlen, out, N, M, S);
    }
}

// Round 14
// 67.832 us; speedup vs baseline: 1.7983x; 1.1966x over previous
//
#include <hip/hip_runtime.h>

using u16 = unsigned short;
using u32 = unsigned int;
using u64 = unsigned long long;

// Fixed problem shape (guarded in the launcher; generic fallback otherwise).
constexpr int Bc = 2, Tc = 8, Fc = 5, Mc = 128, Sc = 128;
constexpr int Np = 65536;           // points per (b,t) slab
constexpr int CPTS = 512;           // points per chunk (8 per lane)
constexpr int NCHK = Np / CPTS;     // 128 chunks per slab

// Largest x with __fsqrt_rn(x) <= r (monotone correctly-rounded sqrt =>
// d2 <= sqrt_ub(r)  <=>  __fsqrt_rn(d2) <= r : the reference predicate, bit-exact).
__device__ __forceinline__ float sqrt_ub(float r) {
    float u = __fmul_rn(r, r);
    if (__fsqrt_rn(u) <= r) {
        while (true) {
            float nu = __uint_as_float(__float_as_uint(u) + 1u);
            if (__fsqrt_rn(nu) <= r) u = nu; else break;
        }
    } else {
        while (__fsqrt_rn(u) > r) u = __uint_as_float(__float_as_uint(u) - 1u);
    }
    return u;
}

__device__ __forceinline__ float box_radius(const float* __restrict__ box) {
    const float hl = __fmul_rn(0.5f, box[3]);
    const float hw = __fmul_rn(0.5f, box[4]);
    return __fmul_rn(__fsqrt_rn(__fadd_rn(__fmul_rn(hl, hl), __fmul_rn(hw, hw))), 1.1f);
}

// One block per (b,t,m) box; 4 waves; wave wv owns chunks c with (c&3)==wv.
// Geometric stages: A = chunks 0..7 (4K pts), B = 8..31 (+12K), C = 32..127
// (+48K). Counting loads ALL 20 float4s of a 2-chunk group into registers
// before computing (batched latency); masks -> LDS; stage exits use one
// shared 128-wide prefix + winners-only mask-emit (R13-verified math).
__global__ __launch_bounds__(256, 4) void k_box(
    const float* __restrict__ points,        // [B,T,N,F]
    const float* __restrict__ rois,          // [B,T,M,7]
    const int*   __restrict__ vlen,          // [B,T,M]
    float*       __restrict__ out)           // [B,M,T,S,F]
{
    const int blk = blockIdx.x;
    const int bt = blk & 15;                 // slab -> XCD pinning (blk%8 == bt%8)
    const int m  = blk >> 4;
    const int t = bt & 7, b = bt >> 3;

    int t_eff = t;
    if (t != 0 && vlen[bt * Mc + m] == 0) t_eff = 0;   // frame-0 fallback
    const int btE = b * Tc + t_eff;

    const float* box = rois + (size_t)(btE * Mc + m) * 7;
    const float cx = box[0], cy = box[1];
    const float T = sqrt_ub(box_radius(box));
    const float* pts = points + (size_t)btE * Np * Fc;
    float* orow = out + (size_t)((b * Mc + m) * Tc + t) * (Sc * Fc);

    __shared__ u64 s_bal[NCHK][8];           // 8 KB ballot masks, index h*4+k
    __shared__ u16 s_cnt[NCHK];              // per-chunk hit counts

    const int tid = threadIdx.x, lane = tid & 63, wv = tid >> 6;
    const u64 lt = (1ull << lane) - 1ull;

    // ---- compute masks/count for chunk c from 10 preloaded float4s ---------
    auto process = [&](int c, const float4* v) {
        int cc = 0;
        #pragma unroll
        for (int h = 0; h < 2; ++h) {
            const float4 v0 = v[h*5+0], v1 = v[h*5+1], v2 = v[h*5+2],
                         v3 = v[h*5+3], v4 = v[h*5+4];
            const float qx0 = v0.x, qy0 = v0.y;
            const float qx1 = v1.y, qy1 = v1.z;
            const float qx2 = v2.z, qy2 = v2.w;
            const float qx3 = v3.w, qy3 = v4.x;
            #pragma unroll
            for (int k = 0; k < 4; ++k) {
                const float qx = k == 0 ? qx0 : k == 1 ? qx1 : k == 2 ? qx2 : qx3;
                const float qy = k == 0 ? qy0 : k == 1 ? qy1 : k == 2 ? qy2 : qy3;
                const float dx = __fsub_rn(qx, cx);
                const float dy = __fsub_rn(qy, cy);
                const float d2 = __fadd_rn(__fmul_rn(dx, dx), __fmul_rn(dy, dy));
                const u64 bb = __ballot(d2 <= T);
                if (lane == 0) s_bal[c][h * 4 + k] = bb;
                cc += (int)__popcll(bb);
            }
        }
        if (lane == 0) s_cnt[c] = (u16)cc;
    };

    // ---- count two chunks: issue ALL 20 loads, then compute ----------------
    auto count2 = [&](int ca, int cb) {
        const float* pa = pts + (size_t)ca * CPTS * Fc;
        const float* pb = pts + (size_t)cb * CPTS * Fc;
        float4 va[10], vb[10];
        #pragma unroll
        for (int h = 0; h < 2; ++h) {
            const float4* sa = (const float4*)(pa + (size_t)(h * 256 + lane * 4) * Fc);
            const float4* sb = (const float4*)(pb + (size_t)(h * 256 + lane * 4) * Fc);
            #pragma unroll
            for (int q = 0; q < 5; ++q) { va[h*5+q] = sa[q]; vb[h*5+q] = sb[q]; }
        }
        process(ca, va);
        process(cb, vb);
    };

    // ---- emit chunk c's winners from stored masks (R13-verified) -----------
    auto emit_chunk = [&](int c, int sb) {
        #pragma unroll
        for (int h = 0; h < 2; ++h) {
            const u64 b0 = s_bal[c][h*4+0];
            const u64 b1 = s_bal[c][h*4+1];
            const u64 b2 = s_bal[c][h*4+2];
            const u64 b3 = s_bal[c][h*4+3];
            const int below = (int)(__popcll(b0 & lt) + __popcll(b1 & lt) +
                                    __popcll(b2 & lt) + __popcll(b3 & lt));
            const int pidx0 = c * CPTS + h * 256 + lane * 4;
            int ownpre = 0;
            #pragma unroll
            for (int k = 0; k < 4; ++k) {
                const u64 bk = k == 0 ? b0 : k == 1 ? b1 : k == 2 ? b2 : b3;
                if ((bk >> lane) & 1ull) {
                    const int slot = sb + below + ownpre;
                    if (slot < Sc) {
                        const float* p = pts + (size_t)(pidx0 + k) * Fc;
                        float* o = orow + (size_t)slot * Fc;
                        o[0] = p[0]; o[1] = p[1]; o[2] = p[2]; o[3] = p[3]; o[4] = p[4];
                    }
                    ++ownpre;
                }
            }
            sb += (int)(__popcll(b0) + __popcll(b1) + __popcll(b2) + __popcll(b3));
        }
    };

    // ---- 128-wide prefix over s_cnt (2 u16 per lane) -----------------------
    int p_excl, p_av, p_total;
    auto prefix128 = [&]() {
        const u32 two = ((const u32*)s_cnt)[lane];
        p_av = (int)(two & 0xFFFFu);
        const int av2 = (int)(two >> 16);
        const int ssum = p_av + av2;
        int incl = ssum;
        #pragma unroll
        for (int d = 1; d < 64; d <<= 1) { int v = __shfl_up(incl, d); if (lane >= d) incl += v; }
        p_excl  = incl - ssum;               // base of chunk 2*lane
        p_total = __shfl(incl, 63);
    };

    // ---- winners-only emit over all owned chunks (uses prefix results) -----
    auto emit_all = [&]() {
        for (int j = 0; j < 32; ++j) {
            const int c = 4 * j + wv;
            if ((int)s_cnt[c] == 0) continue;
            const int sl = c >> 1;
            int base = __shfl(p_excl, sl);
            if (c & 1) base += __shfl(p_av, sl);
            if (base >= Sc) break;           // bases monotone per wave
            emit_chunk(c, base);
        }
    };

    // ================= Stage A: chunks 0..7 (4096 points) ===================
    if (tid < 96) s_cnt[32 + tid] = 0;       // zero C-range before any prefix
    count2(wv, 4 + wv);
    __syncthreads();

    int pre[9];
    pre[0] = 0;
    #pragma unroll
    for (int k = 0; k < 8; ++k) pre[k + 1] = pre[k] + (int)s_cnt[k];

    if (pre[8] >= Sc) {
        if (pre[wv] < Sc)     emit_chunk(wv,     pre[wv]);
        if (pre[4 + wv] < Sc) emit_chunk(4 + wv, pre[4 + wv]);
        return;
    }

    // ================= Stage B: chunks 8..31 (+12288 points) ================
    count2( 8 + wv, 12 + wv);
    count2(16 + wv, 20 + wv);
    count2(24 + wv, 28 + wv);
    __syncthreads();
    prefix128();                             // chunks >=32 read as 0
    if (p_total >= Sc) { emit_all(); return; }

    // ================= Stage C: chunks 32..127 (+49152 points) ==============
    for (int g = 0; g < 12; ++g)
        count2(32 + 8 * g + wv, 36 + 8 * g + wv);
    __syncthreads();
    prefix128();
    emit_all();

    // tail zero [min(total,S), S)
    const int fill = p_total < Sc ? p_total : Sc;
    for (int i = fill * Fc + tid; i < Sc * Fc; i += 256) orow[i] = 0.0f;
}

// ---------------- fallback: R2 single-kernel path (shape-generic) ------------
__global__ __launch_bounds__(1024) void vox_pool(
    const float* __restrict__ points, const float* __restrict__ rois,
    const int* __restrict__ valid_length, float* __restrict__ out,
    int N, int M, int S)
{
    const int blk = blockIdx.x;
    const int m = blk % M;
    const int t = (blk / M) % Tc;
    const int b = blk / (M * Tc);
    int t_eff = t;
    if (t != 0 && valid_length[(b * Tc + t) * M + m] == 0) t_eff = 0;
    const float* box = rois + (size_t)((b * Tc + t_eff) * M + m) * 7;
    const float cx = box[0], cy = box[1];
    const float r = box_radius(box);
    const float* pts = points + (size_t)(b * Tc + t_eff) * N * Fc;
    float* o = out + ((size_t)(b * M + m) * Tc + t) * (size_t)S * Fc;
    __shared__ int wcnt[16];
    const int tid = threadIdx.x, lane = tid & 63, wav = tid >> 6;
    const int nthreads = blockDim.x, nwaves = nthreads >> 6;
    int cnt = 0;
    for (int basei = 0; basei < N; basei += nthreads) {
        const int idx = basei + tid;
        bool inside = false;
        if (idx < N) {
            const float dx = __fsub_rn(pts[(size_t)idx * Fc + 0], cx);
            const float dy = __fsub_rn(pts[(size_t)idx * Fc + 1], cy);
            const float d2 = __fadd_rn(__fmul_rn(dx, dx), __fmul_rn(dy, dy));
            inside = (__fsqrt_rn(d2) <= r);
        }
        const unsigned long long bal = __ballot(inside);
        if (lane == 0) wcnt[wav] = __popcll(bal);
        __syncthreads();
        int wave_off = 0, block_tot = 0;
        for (int w = 0; w < nwaves; ++w) {
            const int c = wcnt[w];
            if (w < wav) wave_off += c;
            block_tot += c;
        }
        if (inside) {
            const int slot = cnt + wave_off + (int)__popcll(bal & ((1ull << lane) - 1ull));
            if (slot < S)
                for (int f = 0; f < Fc; ++f)
                    o[(size_t)slot * Fc + f] = pts[(size_t)idx * Fc + f];
        }
        cnt += block_tot;
        __syncthreads();
        if (cnt >= S) break;
    }
    const int filled = cnt < S ? cnt : S;
    for (int s = filled + tid; s < S; s += nthreads)
        for (int f = 0; f < Fc; ++f)
            o[(size_t)s * Fc + f] = 0.0f;
}

extern "C" void kernel_launch(void* const* d_in, const int* in_sizes, int n_in,
                              void* d_out, int out_size, void* d_ws, size_t ws_size,
                              hipStream_t stream) {
    const float* points = (const float*)d_in[0];
    const float* rois   = (const float*)d_in[1];
    const int*   vlen   = (const int*)d_in[2];
    float* out = (float*)d_out;

    const bool fixed =
        in_sizes[0] == Bc * Tc * Np * Fc &&
        in_sizes[1] == Bc * Tc * Mc * 7 &&
        in_sizes[2] == Bc * Tc * Mc &&
        out_size    == Bc * Mc * Tc * Sc * Fc;

    if (fixed) {
        k_box<<<dim3(Bc * Tc * Mc), 256, 0, stream>>>(points, rois, vlen, out);
    } else {
        const int N = in_sizes[0] / (Bc * Tc * Fc);
        const int M = in_sizes[2] / (Bc * Tc);
        const int S = out_size / (Bc * M * Tc * Fc);
        vox_pool<<<dim3(Bc * Tc * M), 1024, 0, stream>>>(points, rois, vlen, out, N, M, S);
    }
}

// Round 15
// 54.968 us; speedup vs baseline: 2.2191x; 1.2340x over previous
//
#include <hip/hip_runtime.h>

using u16 = unsigned short;
using u32 = unsigned int;
using u64 = unsigned long long;

// Fixed problem shape (guarded in the launcher; generic fallback otherwise).
constexpr int Bc = 2, Tc = 8, Fc = 5, Mc = 128, Sc = 128;
constexpr int Np = 65536;           // points per (b,t) slab
constexpr int CPTS = 256;           // points per chunk (4 per lane, one 5xfloat4 batch)
constexpr int NCHK = Np / CPTS;     // 256 chunks per slab
constexpr int NW = 16;              // waves per block

// Largest x with __fsqrt_rn(x) <= r (monotone correctly-rounded sqrt =>
// d2 <= sqrt_ub(r)  <=>  __fsqrt_rn(d2) <= r : the reference predicate, bit-exact).
__device__ __forceinline__ float sqrt_ub(float r) {
    float u = __fmul_rn(r, r);
    if (__fsqrt_rn(u) <= r) {
        while (true) {
            float nu = __uint_as_float(__float_as_uint(u) + 1u);
            if (__fsqrt_rn(nu) <= r) u = nu; else break;
        }
    } else {
        while (__fsqrt_rn(u) > r) u = __uint_as_float(__float_as_uint(u) - 1u);
    }
    return u;
}

__device__ __forceinline__ float box_radius(const float* __restrict__ box) {
    const float hl = __fmul_rn(0.5f, box[3]);
    const float hw = __fmul_rn(0.5f, box[4]);
    return __fmul_rn(__fsqrt_rn(__fadd_rn(__fmul_rn(hl, hl), __fmul_rn(hw, hw))), 1.1f);
}

// One block per (b,t,m) box; 16 waves; wave wv owns chunks c with c%16==wv.
// Chunk = 256 pts = ONE 5xfloat4 load batch per lane (single memory round
// trip; cross-wave overlap supplies MLP). Geometric stages A/B/C = chunks
// 0..15 / 16..111 / 112..255 (4K / 28K / 64K pts). Masks -> LDS; stage exits
// use a 256-wide shfl prefix + winners-only mask-emit (R13-verified math).
__global__ __launch_bounds__(1024) void k_box(
    const float* __restrict__ points,        // [B,T,N,F]
    const float* __restrict__ rois,          // [B,T,M,7]
    const int*   __restrict__ vlen,          // [B,T,M]
    float*       __restrict__ out)           // [B,M,T,S,F]
{
    const int blk = blockIdx.x;
    const int bt = blk & 15;                 // slab -> XCD pinning (blk%8 == bt%8)
    const int m  = blk >> 4;
    const int t = bt & 7, b = bt >> 3;

    int t_eff = t;
    if (t != 0 && vlen[bt * Mc + m] == 0) t_eff = 0;   // frame-0 fallback
    const int btE = b * Tc + t_eff;

    const float* box = rois + (size_t)(btE * Mc + m) * 7;
    const float cx = box[0], cy = box[1];
    const float T = sqrt_ub(box_radius(box));
    const float* pts = points + (size_t)btE * Np * Fc;
    float* orow = out + (size_t)((b * Mc + m) * Tc + t) * (Sc * Fc);

    __shared__ u64 s_bal[NCHK][4];           // 8 KB ballot masks (k = 0..3)
    __shared__ u16 s_cnt[NCHK];              // per-chunk hit counts

    const int tid = threadIdx.x, lane = tid & 63, wv = tid >> 6;
    const u64 lt = (1ull << lane) - 1ull;

    // ---- count one 256-pt chunk: ONE 5xfloat4 batch -> 4 ballots -----------
    auto count_chunk = [&](int c) {
        const float4* src = (const float4*)(pts + ((size_t)c * CPTS + lane * 4) * Fc);
        const float4 v0 = src[0], v1 = src[1], v2 = src[2], v3 = src[3], v4 = src[4];
        const float qx0 = v0.x, qy0 = v0.y;
        const float qx1 = v1.y, qy1 = v1.z;
        const float qx2 = v2.z, qy2 = v2.w;
        const float qx3 = v3.w, qy3 = v4.x;
        int cc = 0;
        #pragma unroll
        for (int k = 0; k < 4; ++k) {
            const float qx = k == 0 ? qx0 : k == 1 ? qx1 : k == 2 ? qx2 : qx3;
            const float qy = k == 0 ? qy0 : k == 1 ? qy1 : k == 2 ? qy2 : qy3;
            const float dx = __fsub_rn(qx, cx);
            const float dy = __fsub_rn(qy, cy);
            const float d2 = __fadd_rn(__fmul_rn(dx, dx), __fmul_rn(dy, dy));
            const u64 bb = __ballot(d2 <= T);
            if (lane == 0) s_bal[c][k] = bb;
            cc += (int)__popcll(bb);
        }
        if (lane == 0) s_cnt[c] = (u16)cc;
    };

    // ---- emit chunk c's winners from stored masks (R13-verified math) ------
    // point index = c*256 + 4*lane + k; slot = base + below(lanes<l) + ownpre.
    auto emit_chunk = [&](int c, int sb) {
        const u64 b0 = s_bal[c][0], b1 = s_bal[c][1];
        const u64 b2 = s_bal[c][2], b3 = s_bal[c][3];
        const int below = (int)(__popcll(b0 & lt) + __popcll(b1 & lt) +
                                __popcll(b2 & lt) + __popcll(b3 & lt));
        const int pidx0 = c * CPTS + lane * 4;
        int ownpre = 0;
        #pragma unroll
        for (int k = 0; k < 4; ++k) {
            const u64 bk = k == 0 ? b0 : k == 1 ? b1 : k == 2 ? b2 : b3;
            if ((bk >> lane) & 1ull) {
                const int slot = sb + below + ownpre;
                if (slot < Sc) {
                    const float* p = pts + (size_t)(pidx0 + k) * Fc;
                    float* o = orow + (size_t)slot * Fc;
                    o[0] = p[0]; o[1] = p[1]; o[2] = p[2]; o[3] = p[3]; o[4] = p[4];
                }
                ++ownpre;
            }
        }
    };

    // ---- 256-wide prefix over s_cnt (4 u16 per lane) -----------------------
    int p_excl, p_a0, p_a1, p_a2, p_total;
    auto prefix256 = [&]() {
        const u64 four = ((const u64*)s_cnt)[lane];
        p_a0 = (int)(four & 0xFFFFu);
        p_a1 = (int)((four >> 16) & 0xFFFFu);
        p_a2 = (int)((four >> 32) & 0xFFFFu);
        const int a3 = (int)(four >> 48);
        const int ssum = p_a0 + p_a1 + p_a2 + a3;
        int incl = ssum;
        #pragma unroll
        for (int d = 1; d < 64; d <<= 1) { int v = __shfl_up(incl, d); if (lane >= d) incl += v; }
        p_excl  = incl - ssum;               // base of chunk 4*lane
        p_total = __shfl(incl, 63);
    };

    // ---- winners-only emit over owned chunks (c % 16 == wv) ----------------
    auto emit_all = [&]() {
        for (int j = 0; j < NCHK / NW; ++j) {
            const int c = NW * j + wv;
            if ((int)s_cnt[c] == 0) continue;
            const int sl = c >> 2, ci = c & 3;
            int base = __shfl(p_excl, sl);
            if (ci > 0) base += __shfl(p_a0, sl);
            if (ci > 1) base += __shfl(p_a1, sl);
            if (ci > 2) base += __shfl(p_a2, sl);
            if (base >= Sc) break;           // bases monotone per wave
            emit_chunk(c, base);
        }
    };

    // ================= Stage A: chunks 0..15 (4096 points) ==================
    if (tid >= NW && tid < NCHK) s_cnt[tid] = 0;   // zero B/C range
    count_chunk(wv);
    __syncthreads();
    prefix256();
    __syncthreads();                          // prefix reads done before B writes
    if (p_total >= Sc) { emit_all(); return; }

    // ================= Stage B: chunks 16..111 (+24576 points) ==============
    #pragma unroll
    for (int j = 0; j < 6; ++j) count_chunk(16 + NW * j + wv);
    __syncthreads();
    prefix256();
    __syncthreads();                          // prefix reads done before C writes
    if (p_total >= Sc) { emit_all(); return; }

    // ================= Stage C: chunks 112..255 (+36864 points) =============
    #pragma unroll
    for (int j = 0; j < 9; ++j) count_chunk(112 + NW * j + wv);
    __syncthreads();
    prefix256();
    emit_all();

    // tail zero [min(total,S), S)
    const int fill = p_total < Sc ? p_total : Sc;
    for (int i = fill * Fc + tid; i < Sc * Fc; i += 1024) orow[i] = 0.0f;
}

// ---------------- fallback: R2 single-kernel path (shape-generic) ------------
__global__ __launch_bounds__(1024) void vox_pool(
    const float* __restrict__ points, const float* __restrict__ rois,
    const int* __restrict__ valid_length, float* __restrict__ out,
    int N, int M, int S)
{
    const int blk = blockIdx.x;
    const int m = blk % M;
    const int t = (blk / M) % Tc;
    const int b = blk / (M * Tc);
    int t_eff = t;
    if (t != 0 && valid_length[(b * Tc + t) * M + m] == 0) t_eff = 0;
    const float* box = rois + (size_t)((b * Tc + t_eff) * M + m) * 7;
    const float cx = box[0], cy = box[1];
    const float r = box_radius(box);
    const float* pts = points + (size_t)(b * Tc + t_eff) * N * Fc;
    float* o = out + ((size_t)(b * M + m) * Tc + t) * (size_t)S * Fc;
    __shared__ int wcnt[16];
    const int tid = threadIdx.x, lane = tid & 63, wav = tid >> 6;
    const int nthreads = blockDim.x, nwaves = nthreads >> 6;
    int cnt = 0;
    for (int basei = 0; basei < N; basei += nthreads) {
        const int idx = basei + tid;
        bool inside = false;
        if (idx < N) {
            const float dx = __fsub_rn(pts[(size_t)idx * Fc + 0], cx);
            const float dy = __fsub_rn(pts[(size_t)idx * Fc + 1], cy);
            const float d2 = __fadd_rn(__fmul_rn(dx, dx), __fmul_rn(dy, dy));
            inside = (__fsqrt_rn(d2) <= r);
        }
        const unsigned long long bal = __ballot(inside);
        if (lane == 0) wcnt[wav] = __popcll(bal);
        __syncthreads();
        int wave_off = 0, block_tot = 0;
        for (int w = 0; w < nwaves; ++w) {
            const int c = wcnt[w];
            if (w < wav) wave_off += c;
            block_tot += c;
        }
        if (inside) {
            const int slot = cnt + wave_off + (int)__popcll(bal & ((1ull << lane) - 1ull));
            if (slot < S)
                for (int f = 0; f < Fc; ++f)
                    o[(size_t)slot * Fc + f] = pts[(size_t)idx * Fc + f];
        }
        cnt += block_tot;
        __syncthreads();
        if (cnt >= S) break;
    }
    const int filled = cnt < S ? cnt : S;
    for (int s = filled + tid; s < S; s += nthreads)
        for (int f = 0; f < Fc; ++f)
            o[(size_t)s * Fc + f] = 0.0f;
}

extern "C" void kernel_launch(void* const* d_in, const int* in_sizes, int n_in,
                              void* d_out, int out_size, void* d_ws, size_t ws_size,
                              hipStream_t stream) {
    const float* points = (const float*)d_in[0];
    const float* rois   = (const float*)d_in[1];
    const int*   vlen   = (const int*)d_in[2];
    float* out = (float*)d_out;

    const bool fixed =
        in_sizes[0] == Bc * Tc * Np * Fc &&
        in_sizes[1] == Bc * Tc * Mc * 7 &&
        in_sizes[2] == Bc * Tc * Mc &&
        out_size    == Bc * Mc * Tc * Sc * Fc;

    if (fixed) {
        k_box<<<dim3(Bc * Tc * Mc), 1024, 0, stream>>>(points, rois, vlen, out);
    } else {
        const int N = in_sizes[0] / (Bc * Tc * Fc);
        const int M = in_sizes[2] / (Bc * Tc);
        const int S = out_size / (Bc * M * Tc * Fc);
        vox_pool<<<dim3(Bc * Tc * M), 1024, 0, stream>>>(points, rois, vlen, out, N, M, S);
    }
}